// Round 7
// baseline (199.710 us; speedup 1.0000x reference)
//
#include <hip/hip_runtime.h>
#include <stdint.h>

#define NH   16
#define EMB  1024
#define HD   64
#define BSZ  2
#define SEQ  2048
#define NROW (BSZ * SEQ)          // 4096

typedef __attribute__((ext_vector_type(8))) short bf16x8;   // 8 bf16 = 4 VGPRs
typedef __attribute__((ext_vector_type(4))) float f32x4;    // MFMA C/D

__device__ __forceinline__ uint16_t f2bf(float f) {
    union { float f; uint32_t i; } v; v.f = f;
    uint32_t r = v.i + 0x7FFFu + ((v.i >> 16) & 1u);  // RNE
    return (uint16_t)(r >> 16);
}
__device__ __forceinline__ uint32_t pack2(float a, float b) {
    return (uint32_t)f2bf(a) | ((uint32_t)f2bf(b) << 16);
}
// round-half-up pack (5 ops): fine for P in [0,1]
__device__ __forceinline__ uint32_t pack2r(float a, float b) {
    union { float f; uint32_t i; } ua, ub; ua.f = a; ub.f = b;
    return ((ua.i + 0x8000u) >> 16) | ((ub.i + 0x8000u) & 0xFFFF0000u);
}

// =====================================================================
// Prep A: X fp32 -> bf16 (8 elems / thread)
// =====================================================================
__global__ __launch_bounds__(256) void convert_x(
    const float* __restrict__ X, uint16_t* __restrict__ Xbf)
{
    size_t idx = ((size_t)blockIdx.x * 256 + threadIdx.x) * 8;
    float4 a = *(const float4*)&X[idx];
    float4 b = *(const float4*)&X[idx + 4];
    *(uint4*)&Xbf[idx] = make_uint4(pack2(a.x, a.y), pack2(a.z, a.w),
                                    pack2(b.x, b.y), pack2(b.z, b.w));
}

// =====================================================================
// Prep B: W[k][n] fp32 -> Wt[n][k] bf16 (64x64 tiles via LDS).
// blocks 0..255 -> Wq, 256..271 -> Wk, 272..287 -> Wv.
// =====================================================================
__global__ __launch_bounds__(256) void transpose_w(
    const float* __restrict__ Wq, const float* __restrict__ Wk,
    const float* __restrict__ Wv, uint16_t* __restrict__ Wqt,
    uint16_t* __restrict__ Wkt, uint16_t* __restrict__ Wvt)
{
    const int id = blockIdx.x, tid = threadIdx.x;
    const float* W; uint16_t* Wt; int k0, n0, ldw;
    if (id < 256)      { W = Wq; Wt = Wqt; k0 = (id >> 4) * 64; n0 = (id & 15) * 64; ldw = EMB; }
    else if (id < 272) { W = Wk; Wt = Wkt; k0 = (id - 256) * 64; n0 = 0; ldw = HD; }
    else               { W = Wv; Wt = Wvt; k0 = (id - 272) * 64; n0 = 0; ldw = HD; }

    __shared__ uint16_t T[64][72];
    const int r = tid >> 2, c4 = (tid & 3) * 16;
#pragma unroll
    for (int i = 0; i < 4; ++i) {
        float4 wv = *(const float4*)&W[(size_t)(k0 + r) * ldw + n0 + c4 + 4 * i];
        T[r][c4 + 4 * i + 0] = f2bf(wv.x); T[r][c4 + 4 * i + 1] = f2bf(wv.y);
        T[r][c4 + 4 * i + 2] = f2bf(wv.z); T[r][c4 + 4 * i + 3] = f2bf(wv.w);
    }
    __syncthreads();
    const int n = tid >> 2, kk = (tid & 3) * 16;
    uint32_t o[8];
#pragma unroll
    for (int i = 0; i < 8; ++i)
        o[i] = (uint32_t)T[kk + 2 * i][n] | ((uint32_t)T[kk + 2 * i + 1][n] << 16);
    uint16_t* dst = &Wt[(size_t)(n0 + n) * EMB + k0 + kk];
    *(uint4*)dst       = make_uint4(o[0], o[1], o[2], o[3]);
    *(uint4*)(dst + 8) = make_uint4(o[4], o[5], o[6], o[7]);
}

// =====================================================================
// Kernel 1: MFMA projection GEMM, 128x128 tiles, BK=32 (unchanged R6).
// =====================================================================
__global__ __launch_bounds__(256) void qkv_gemm_mfma(
    const uint16_t* __restrict__ Xbf, const uint16_t* __restrict__ Wqt,
    const uint16_t* __restrict__ Wkt, const uint16_t* __restrict__ Wvt,
    float* __restrict__ Qout, uint16_t* __restrict__ Kbf,
    uint16_t* __restrict__ Vtbf)
{
    const int tid  = threadIdx.x;
    const int w    = tid >> 6, lane = tid & 63;
    const int l    = lane & 15, quad = lane >> 4;
    const int wm   = w & 1, wn = w >> 1;
    const int nt   = blockIdx.x;
    const int m0   = blockIdx.y * 128;

    __shared__ uint16_t As[128][40];
    __shared__ uint16_t Bs[128][40];

    f32x4 acc[4][4] = {};
    const int sr = tid >> 1, kh = (tid & 1) * 16;

    for (int k0 = 0; k0 < EMB; k0 += 32) {
        {
            const uint4* src = (const uint4*)&Xbf[(size_t)(m0 + sr) * EMB + k0 + kh];
            uint4 a0 = src[0], a1 = src[1];
            *(uint4*)&As[sr][kh] = a0; *(uint4*)&As[sr][kh + 8] = a1;
        }
        {
            const uint16_t* src;
            if (nt < 8)       src = &Wqt[(size_t)(nt * 128 + sr) * EMB + k0 + kh];
            else if (sr < 64) src = &Wkt[(size_t)sr * EMB + k0 + kh];
            else              src = &Wvt[(size_t)(sr - 64) * EMB + k0 + kh];
            uint4 b0 = ((const uint4*)src)[0], b1 = ((const uint4*)src)[1];
            *(uint4*)&Bs[sr][kh] = b0; *(uint4*)&Bs[sr][kh + 8] = b1;
        }
        __syncthreads();

        bf16x8 af[4], bf[4];
#pragma unroll
        for (int i = 0; i < 4; ++i)
            af[i] = *(const bf16x8*)&As[64 * wm + 16 * i + l][quad * 8];
#pragma unroll
        for (int j = 0; j < 4; ++j)
            bf[j] = *(const bf16x8*)&Bs[64 * wn + 16 * j + l][quad * 8];
#pragma unroll
        for (int i = 0; i < 4; ++i)
#pragma unroll
            for (int j = 0; j < 4; ++j)
                acc[i][j] = __builtin_amdgcn_mfma_f32_16x16x32_bf16(
                    af[i], bf[j], acc[i][j], 0, 0, 0);
        __syncthreads();
    }

    if (nt < 8) {
#pragma unroll
        for (int i = 0; i < 4; ++i)
#pragma unroll
            for (int j = 0; j < 4; ++j)
#pragma unroll
                for (int r = 0; r < 4; ++r)
                    Qout[(size_t)(m0 + 64 * wm + 16 * i + 4 * quad + r) * EMB
                         + nt * 128 + 64 * wn + 16 * j + l] = acc[i][j][r];
    } else if (wn == 0) {
#pragma unroll
        for (int i = 0; i < 4; ++i)
#pragma unroll
            for (int j = 0; j < 4; ++j)
#pragma unroll
                for (int r = 0; r < 4; ++r)
                    Kbf[(size_t)(m0 + 64 * wm + 16 * i + 4 * quad + r) * HD
                        + 16 * j + l] = f2bf(acc[i][j][r]);
    } else {
#pragma unroll
        for (int i = 0; i < 4; ++i)
#pragma unroll
            for (int j = 0; j < 4; ++j)
#pragma unroll
                for (int r = 0; r < 4; ++r)
                    Vtbf[(size_t)(16 * j + l) * NROW
                         + m0 + 64 * wm + 16 * i + 4 * quad + r] = f2bf(acc[i][j][r]);
    }
}

// =====================================================================
// Kernel 1 (fallback, proven R5): fp32 vector projection GEMM.
// =====================================================================
__global__ __launch_bounds__(256) void qkv_gemm_vec(
    const float* __restrict__ X,  const float* __restrict__ Wq,
    const float* __restrict__ Wk, const float* __restrict__ Wv,
    float* __restrict__ Qout, uint16_t* __restrict__ Kbf,
    uint16_t* __restrict__ Vtbf)
{
    const int tid = threadIdx.x;
    const int tx = tid & 15, ty = tid >> 4;
    const int bx = blockIdx.x;
    const int m0 = blockIdx.y * 64;

    const float* W; int ldw, n0;
    if (bx < 16)       { W = Wq; ldw = EMB; n0 = bx * 64; }
    else if (bx == 16) { W = Wk; ldw = HD;  n0 = 0; }
    else               { W = Wv; ldw = HD;  n0 = 0; }

    __shared__ float sA[64][17];
    __shared__ float sB[16][64];

    float acc[4][4] = {};
    const int arow = tid >> 2, acol = (tid & 3) * 4;
    const int brow = tid >> 4, bcol = (tid & 15) * 4;

    for (int k0 = 0; k0 < EMB; k0 += 16) {
        float4 fa = *(const float4*)&X[(size_t)(m0 + arow) * EMB + k0 + acol];
        float4 fb = *(const float4*)&W[(size_t)(k0 + brow) * ldw + n0 + bcol];
        sA[arow][acol + 0] = fa.x; sA[arow][acol + 1] = fa.y;
        sA[arow][acol + 2] = fa.z; sA[arow][acol + 3] = fa.w;
        sB[brow][bcol + 0] = fb.x; sB[brow][bcol + 1] = fb.y;
        sB[brow][bcol + 2] = fb.z; sB[brow][bcol + 3] = fb.w;
        __syncthreads();
#pragma unroll
        for (int kk = 0; kk < 16; ++kk) {
            float a0 = sA[4 * ty + 0][kk];
            float a1 = sA[4 * ty + 1][kk];
            float a2 = sA[4 * ty + 2][kk];
            float a3 = sA[4 * ty + 3][kk];
            float4 b = *(const float4*)&sB[kk][4 * tx];
            acc[0][0] += a0 * b.x; acc[0][1] += a0 * b.y; acc[0][2] += a0 * b.z; acc[0][3] += a0 * b.w;
            acc[1][0] += a1 * b.x; acc[1][1] += a1 * b.y; acc[1][2] += a1 * b.z; acc[1][3] += a1 * b.w;
            acc[2][0] += a2 * b.x; acc[2][1] += a2 * b.y; acc[2][2] += a2 * b.z; acc[2][3] += a2 * b.w;
            acc[3][0] += a3 * b.x; acc[3][1] += a3 * b.y; acc[3][2] += a3 * b.z; acc[3][3] += a3 * b.w;
        }
        __syncthreads();
    }

    if (bx < 16) {
#pragma unroll
        for (int i = 0; i < 4; ++i)
            *(float4*)&Qout[(size_t)(m0 + 4 * ty + i) * EMB + n0 + 4 * tx] =
                make_float4(acc[i][0], acc[i][1], acc[i][2], acc[i][3]);
    } else if (bx == 16) {
#pragma unroll
        for (int i = 0; i < 4; ++i) {
            ushort4 u; u.x = f2bf(acc[i][0]); u.y = f2bf(acc[i][1]);
            u.z = f2bf(acc[i][2]); u.w = f2bf(acc[i][3]);
            *(ushort4*)&Kbf[(size_t)(m0 + 4 * ty + i) * HD + 4 * tx] = u;
        }
    } else {
#pragma unroll
        for (int j = 0; j < 4; ++j) {
            ushort4 u; u.x = f2bf(acc[0][j]); u.y = f2bf(acc[1][j]);
            u.z = f2bf(acc[2][j]); u.w = f2bf(acc[3][j]);
            *(ushort4*)&Vtbf[(size_t)(4 * tx + j) * NROW + m0 + 4 * ty] = u;
        }
    }
}

// =====================================================================
// Kernel 2: causal MQA flash attention, bf16 MFMA, DOUBLE-BUFFERED K/V.
// One barrier per k-tile; next tile's global loads issued before compute
// (latency hidden), written to the spare buffer after compute.
// Q is pre-scaled by 0.125*log2e at staging (S comes out exp2-ready).
// qb reversed so longest blocks launch first.
// =====================================================================
__global__ __launch_bounds__(256) void mqa_attn(
    const uint16_t* __restrict__ Kbf, const uint16_t* __restrict__ Vtbf,
    float* __restrict__ Out)
{
    const int tid  = threadIdx.x;
    const int w    = tid >> 6;
    const int lane = tid & 63;
    const int l    = lane & 15;
    const int quad = lane >> 4;
    const int qb = (int)gridDim.x - 1 - (int)blockIdx.x;   // longest first
    const int h = blockIdx.y, b = blockIdx.z;
    const int q0 = qb * 64;

    __shared__ __align__(16) uint16_t Ps[64][72];          // P [m][t]
    __shared__ __align__(16) uint16_t KV[2][2][64][72];    // [buf][K|Vt]

    const float C = 0.125f * 1.4426950408889634f;          // scale * log2e
    const int sr = tid >> 2, sc = (tid & 3) * 16;          // staging row/col

    // ---- stage Q (pre-scaled) into KV[1][0]; stage K/V tile 0 into KV[0] ----
    {
        const float* src = &Out[(size_t)(b * SEQ + q0 + sr) * EMB + h * HD + sc];
        float4 f0 = *(const float4*)(src + 0);
        float4 f1 = *(const float4*)(src + 4);
        float4 f2 = *(const float4*)(src + 8);
        float4 f3 = *(const float4*)(src + 12);
        *(uint4*)&KV[1][0][sr][sc] =
            make_uint4(pack2(f0.x * C, f0.y * C), pack2(f0.z * C, f0.w * C),
                       pack2(f1.x * C, f1.y * C), pack2(f1.z * C, f1.w * C));
        *(uint4*)&KV[1][0][sr][sc + 8] =
            make_uint4(pack2(f2.x * C, f2.y * C), pack2(f2.z * C, f2.w * C),
                       pack2(f3.x * C, f3.y * C), pack2(f3.z * C, f3.w * C));
        const uint4* ks = (const uint4*)&Kbf[(size_t)(b * SEQ + sr) * HD + sc];
        uint4 k0v = ks[0], k1v = ks[1];
        *(uint4*)&KV[0][0][sr][sc] = k0v; *(uint4*)&KV[0][0][sr][sc + 8] = k1v;
        const uint4* vs = (const uint4*)&Vtbf[(size_t)sr * NROW + b * SEQ + sc];
        uint4 v0v = vs[0], v1v = vs[1];
        *(uint4*)&KV[0][1][sr][sc] = v0v; *(uint4*)&KV[0][1][sr][sc + 8] = v1v;
    }
    __syncthreads();

    // Q B-fragments (persistent)
    bf16x8 qf0 = *(const bf16x8*)&KV[1][0][16 * w + l][quad * 8];
    bf16x8 qf1 = *(const bf16x8*)&KV[1][0][16 * w + l][32 + quad * 8];
    __syncthreads();   // all qf reads done before KV[1] is overwritten

    float m_r = -1e30f, l_r = 0.f;
    f32x4 accO[4] = {{0.f,0.f,0.f,0.f},{0.f,0.f,0.f,0.f},
                     {0.f,0.f,0.f,0.f},{0.f,0.f,0.f,0.f}};
    const int qi_l = 16 * w + l;

    for (int kb = 0; kb <= qb; ++kb) {
        const int cur = kb & 1, nxt = cur ^ 1;
        const bool more = (kb < qb);

        // ---- issue next tile's global loads (latency hidden by compute) ----
        uint4 kg0, kg1, vg0, vg1;
        if (more) {
            const int k0n = (kb + 1) * 64;
            const uint4* ks = (const uint4*)&Kbf[(size_t)(b * SEQ + k0n + sr) * HD + sc];
            kg0 = ks[0]; kg1 = ks[1];
            const uint4* vs = (const uint4*)&Vtbf[(size_t)sr * NROW + b * SEQ + k0n + sc];
            vg0 = vs[0]; vg1 = vs[1];
        }

        // ---- S^T = K · Q^T (S already in log2 domain via pre-scaled Q) ----
        f32x4 accS[4] = {{0.f,0.f,0.f,0.f},{0.f,0.f,0.f,0.f},
                         {0.f,0.f,0.f,0.f},{0.f,0.f,0.f,0.f}};
#pragma unroll
        for (int ts = 0; ts < 4; ++ts) {
            bf16x8 a0 = *(const bf16x8*)&KV[cur][0][16 * ts + l][quad * 8];
            bf16x8 a1 = *(const bf16x8*)&KV[cur][0][16 * ts + l][32 + quad * 8];
            accS[ts] = __builtin_amdgcn_mfma_f32_16x16x32_bf16(a0, qf0, accS[ts], 0, 0, 0);
            accS[ts] = __builtin_amdgcn_mfma_f32_16x16x32_bf16(a1, qf1, accS[ts], 0, 0, 0);
        }

        // ---- online softmax along t ----
        float sv[16];
#pragma unroll
        for (int ts = 0; ts < 4; ++ts)
#pragma unroll
            for (int r = 0; r < 4; ++r) sv[4 * ts + r] = accS[ts][r];
        if (kb == qb) {   // uniform branch: causal mask only on diagonal tile
#pragma unroll
            for (int ts = 0; ts < 4; ++ts)
#pragma unroll
                for (int r = 0; r < 4; ++r)
                    if ((16 * ts + 4 * quad + r) > qi_l) sv[4 * ts + r] = -1e30f;
        }
        float tmax = sv[0];
#pragma unroll
        for (int i = 1; i < 16; ++i) tmax = fmaxf(tmax, sv[i]);
        tmax = fmaxf(tmax, __shfl_xor(tmax, 16));
        tmax = fmaxf(tmax, __shfl_xor(tmax, 32));
        float mnew  = fmaxf(m_r, tmax);
        float alpha = exp2f(m_r - mnew);
        float ssum  = 0.f;
#pragma unroll
        for (int i = 0; i < 16; ++i) {
            float p = exp2f(sv[i] - mnew);
            sv[i] = p; ssum += p;
        }
        ssum += __shfl_xor(ssum, 16);
        ssum += __shfl_xor(ssum, 32);
        l_r = alpha * l_r + ssum;
        m_r = mnew;

        // ---- pack P -> Ps[m][t] (wave-private rows) ----
#pragma unroll
        for (int ts = 0; ts < 4; ++ts) {
            *(uint2*)&Ps[16 * w + l][16 * ts + 4 * quad] =
                make_uint2(pack2r(sv[4 * ts + 0], sv[4 * ts + 1]),
                           pack2r(sv[4 * ts + 2], sv[4 * ts + 3]));
        }

        // ---- rescale O ----
#pragma unroll
        for (int r = 0; r < 4; ++r) {
            float ar = __shfl(alpha, (quad << 2) + r);
#pragma unroll
            for (int tn = 0; tn < 4; ++tn) accO[tn][r] *= ar;
        }

        // ---- O += P · V ----
        bf16x8 pa0 = *(const bf16x8*)&Ps[16 * w + l][quad * 8];
        bf16x8 pa1 = *(const bf16x8*)&Ps[16 * w + l][32 + quad * 8];
#pragma unroll
        for (int tn = 0; tn < 4; ++tn) {
            bf16x8 v0 = *(const bf16x8*)&KV[cur][1][16 * tn + l][quad * 8];
            bf16x8 v1 = *(const bf16x8*)&KV[cur][1][16 * tn + l][32 + quad * 8];
            accO[tn] = __builtin_amdgcn_mfma_f32_16x16x32_bf16(pa0, v0, accO[tn], 0, 0, 0);
            accO[tn] = __builtin_amdgcn_mfma_f32_16x16x32_bf16(pa1, v1, accO[tn], 0, 0, 0);
        }

        // ---- commit staged tile into spare buffer; one barrier per iter ----
        if (more) {
            *(uint4*)&KV[nxt][0][sr][sc]     = kg0;
            *(uint4*)&KV[nxt][0][sr][sc + 8] = kg1;
            *(uint4*)&KV[nxt][1][sr][sc]     = vg0;
            *(uint4*)&KV[nxt][1][sr][sc + 8] = vg1;
        }
        __syncthreads();
    }

    // ---- finalize: O /= l, write fp32 (overwrites this block's Q region) ----
#pragma unroll
    for (int r = 0; r < 4; ++r) {
        float lr  = __shfl(l_r, (quad << 2) + r);
        float inv = 1.0f / lr;
        const int row = q0 + 16 * w + 4 * quad + r;
#pragma unroll
        for (int tn = 0; tn < 4; ++tn)
            Out[(size_t)(b * SEQ + row) * EMB + h * HD + 16 * tn + l] =
                accO[tn][r] * inv;
    }
}

extern "C" void kernel_launch(void* const* d_in, const int* in_sizes, int n_in,
                              void* d_out, int out_size, void* d_ws, size_t ws_size,
                              hipStream_t stream) {
    const float* X  = (const float*)d_in[0];
    const float* Wq = (const float*)d_in[1];
    const float* Wk = (const float*)d_in[2];
    const float* Wv = (const float*)d_in[3];
    float* OutP = (float*)d_out;

    char* ws = (char*)d_ws;
    const size_t MB = 1024 * 1024;
    uint16_t* Xbf  = (uint16_t*)(ws);
    uint16_t* Wqt  = (uint16_t*)(ws + 8 * MB);
    uint16_t* Wkt  = (uint16_t*)(ws + 10 * MB);
    uint16_t* Wvt  = (uint16_t*)(ws + 10 * MB + 256 * 1024);
    uint16_t* KbfF = (uint16_t*)(ws + 10 * MB + 512 * 1024);
    uint16_t* VtbfF= (uint16_t*)(ws + 11 * MB);

    if (ws_size >= 12 * MB) {
        convert_x  <<<2048, 256, 0, stream>>>(X, Xbf);
        transpose_w<<<288, 256, 0, stream>>>(Wq, Wk, Wv, Wqt, Wkt, Wvt);
        qkv_gemm_mfma<<<dim3(9, 32), 256, 0, stream>>>(Xbf, Wqt, Wkt, Wvt,
                                                       OutP, KbfF, VtbfF);
        mqa_attn<<<dim3(SEQ / 64, NH, BSZ), 256, 0, stream>>>(KbfF, VtbfF, OutP);
    } else {
        uint16_t* Kbf  = (uint16_t*)d_ws;
        uint16_t* Vtbf = Kbf + (size_t)NROW * HD;
        qkv_gemm_vec<<<dim3(18, 64), 256, 0, stream>>>(X, Wq, Wk, Wv, OutP, Kbf, Vtbf);
        mqa_attn<<<dim3(SEQ / 64, NH, BSZ), 256, 0, stream>>>(Kbf, Vtbf, OutP);
    }
}